// Round 2
// baseline (9110.249 us; speedup 1.0000x reference)
//
#include <hip/hip_runtime.h>
#include <hip/hip_bf16.h>
#include <math.h>

#define HN 16
#define DM 1024
#define DK 64
#define BSZ 8
#define SEQL 1024
#define QB 8

// ---------------------------------------------------------------------------
// Tiled fp32 GEMM (per batch): C[M,N] = A[M,K] @ W[K,N] + bias[N], M=N=K=1024
// BM=BN=64, BK=16, 256 threads, each thread computes 4x4 outputs.
// remap==1: write C into [h, s, dk] head-split layout (s=m, n=h*64+d)
// remap==0: write C row-major [M, N]
// ---------------------------------------------------------------------------
__global__ __launch_bounds__(256) void gemm_kernel(
    const float* __restrict__ A, const float* __restrict__ W,
    const float* __restrict__ bias, float* __restrict__ C,
    int M, int N, int K, int remap)
{
    __shared__ float As[64][17];
    __shared__ float Bs[16][65];
    const int t = threadIdx.x;
    const int tx = t & 15, ty = t >> 4;
    const int tileM = blockIdx.x * 64, tileN = blockIdx.y * 64;

    float acc[4][4] = {};

    for (int k0 = 0; k0 < K; k0 += 16) {
        for (int l = t; l < 64 * 16; l += 256) {
            int r = l >> 4, c = l & 15;
            As[r][c] = A[(size_t)(tileM + r) * K + k0 + c];
        }
        for (int l = t; l < 16 * 64; l += 256) {
            int r = l >> 6, c = l & 63;
            Bs[r][c] = W[(size_t)(k0 + r) * N + tileN + c];
        }
        __syncthreads();
        #pragma unroll
        for (int kk = 0; kk < 16; ++kk) {
            float a[4], b[4];
            #pragma unroll
            for (int i = 0; i < 4; ++i) a[i] = As[ty * 4 + i][kk];
            #pragma unroll
            for (int j = 0; j < 4; ++j) b[j] = Bs[kk][tx * 4 + j];
            #pragma unroll
            for (int i = 0; i < 4; ++i)
                #pragma unroll
                for (int j = 0; j < 4; ++j)
                    acc[i][j] += a[i] * b[j];
        }
        __syncthreads();
    }

    #pragma unroll
    for (int i = 0; i < 4; ++i) {
        int m = tileM + ty * 4 + i;
        #pragma unroll
        for (int j = 0; j < 4; ++j) {
            int n = tileN + tx * 4 + j;
            float v = acc[i][j] + bias[n];
            if (remap) {
                int h = n >> 6, d = n & 63;
                C[((size_t)h * SEQL + m) * DK + d] = v;
            } else {
                C[(size_t)m * N + n] = v;
            }
        }
    }
}

// ---------------------------------------------------------------------------
// Attention (per batch): one block handles (h, 8 query rows).
// scores[8][1024] in LDS; masked+scaled; per-row softmax; ctx = P @ V.
// ctx written in [s, h*64+d] layout (concat is free).
// ---------------------------------------------------------------------------
__global__ __launch_bounds__(256) void attn_kernel(
    const float* __restrict__ Q, const float* __restrict__ K,
    const float* __restrict__ V, const int* __restrict__ mask,
    float* __restrict__ ctx)
{
    const int blk = blockIdx.x;
    const int nqb = SEQL / QB;          // 128
    const int qb = blk % nqb;
    const int h = blk / nqb;
    const int q0 = qb * QB;
    const int t = threadIdx.x;

    __shared__ float qs[QB][DK];          // 2 KB
    __shared__ float sc[QB][SEQL];        // 32 KB
    __shared__ float red[256];            // 1 KB
    __shared__ float part[4][QB][DK];     // 8 KB
    __shared__ float rinv[QB];

    const float* Qb = Q + ((size_t)h * SEQL + q0) * DK;
    const float* Kb = K + (size_t)h * SEQL * DK;
    const float* Vb = V + (size_t)h * SEQL * DK;
    const int*   mb = mask + (size_t)q0 * SEQL;

    for (int l = t; l < QB * DK; l += 256) qs[l >> 6][l & 63] = Qb[l];
    __syncthreads();

    const float scale = 0.125f;  // 1/sqrt(64)
    for (int j = t; j < SEQL; j += 256) {
        const float* kr = Kb + (size_t)j * DK;
        float acc[QB] = {};
        #pragma unroll
        for (int d4 = 0; d4 < DK; d4 += 4) {
            float4 kv = *(const float4*)(kr + d4);
            #pragma unroll
            for (int r = 0; r < QB; ++r) {
                acc[r] += qs[r][d4 + 0] * kv.x + qs[r][d4 + 1] * kv.y +
                          qs[r][d4 + 2] * kv.z + qs[r][d4 + 3] * kv.w;
            }
        }
        #pragma unroll
        for (int r = 0; r < QB; ++r)
            sc[r][j] = mb[r * SEQL + j] ? acc[r] * scale : -1e9f;
    }
    __syncthreads();

    for (int r = 0; r < QB; ++r) {
        float mx = -1e30f;
        for (int j = t; j < SEQL; j += 256) mx = fmaxf(mx, sc[r][j]);
        red[t] = mx;
        __syncthreads();
        for (int s = 128; s > 0; s >>= 1) {
            if (t < s) red[t] = fmaxf(red[t], red[t + s]);
            __syncthreads();
        }
        mx = red[0];
        __syncthreads();
        float sm = 0.f;
        for (int j = t; j < SEQL; j += 256) {
            float e = __expf(sc[r][j] - mx);
            sc[r][j] = e;
            sm += e;
        }
        red[t] = sm;
        __syncthreads();
        for (int s = 128; s > 0; s >>= 1) {
            if (t < s) red[t] += red[t + s];
            __syncthreads();
        }
        if (t == 0) rinv[r] = 1.0f / red[0];
        __syncthreads();
    }

    const int d = t & 63, c = t >> 6;
    float acc2[QB] = {};
    for (int j = c * 256; j < c * 256 + 256; ++j) {
        float v = Vb[(size_t)j * DK + d];
        #pragma unroll
        for (int r = 0; r < QB; ++r) acc2[r] += sc[r][j] * v;
    }
    #pragma unroll
    for (int r = 0; r < QB; ++r) part[c][r][d] = acc2[r];
    __syncthreads();
    if (c == 0) {
        #pragma unroll
        for (int r = 0; r < QB; ++r) {
            float s = part[0][r][d] + part[1][r][d] + part[2][r][d] + part[3][r][d];
            ctx[(size_t)(q0 + r) * DM + h * DK + d] = s * rinv[r];
        }
    }
}

extern "C" void kernel_launch(void* const* d_in, const int* in_sizes, int n_in,
                              void* d_out, int out_size, void* d_ws, size_t ws_size,
                              hipStream_t stream) {
    const float* q    = (const float*)d_in[0];
    const float* k    = (const float*)d_in[1];
    const float* v    = (const float*)d_in[2];
    const int*   mask = (const int*)d_in[3];
    const float* Wq   = (const float*)d_in[4];
    const float* bq   = (const float*)d_in[5];
    const float* Wk   = (const float*)d_in[6];
    const float* bk   = (const float*)d_in[7];
    const float* Wv   = (const float*)d_in[8];
    const float* bv   = (const float*)d_in[9];
    const float* Wo   = (const float*)d_in[10];
    const float* bo   = (const float*)d_in[11];
    float* out = (float*)d_out;

    // Per-batch scratch: 4 buffers x 4 MB = 16 MB total (ws-size safe).
    const size_t NB = (size_t)SEQL * DM;  // 1M floats = 4 MB
    float* ws   = (float*)d_ws;
    float* Qw   = ws;            // [h, s, dk]
    float* Kw   = ws + NB;       // [h, s, dk]
    float* Vw   = ws + 2 * NB;   // [h, s, dk]
    float* ctxb = ws + 3 * NB;   // [s, dm]

    dim3 gg(SEQL / 64, DM / 64);  // 16 x 16

    for (int b = 0; b < BSZ; ++b) {
        const float* qb_ = q + (size_t)b * NB;
        const float* kb_ = k + (size_t)b * NB;
        const float* vb_ = v + (size_t)b * NB;
        const int*   mb_ = mask + (size_t)b * SEQL * SEQL;
        float*       ob_ = out + (size_t)b * NB;

        gemm_kernel<<<gg, 256, 0, stream>>>(qb_, Wq, bq, Qw, SEQL, DM, DM, 1);
        gemm_kernel<<<gg, 256, 0, stream>>>(kb_, Wk, bk, Kw, SEQL, DM, DM, 1);
        gemm_kernel<<<gg, 256, 0, stream>>>(vb_, Wv, bv, Vw, SEQL, DM, DM, 1);

        attn_kernel<<<HN * (SEQL / QB), 256, 0, stream>>>(Qw, Kw, Vw, mb_, ctxb);

        gemm_kernel<<<gg, 256, 0, stream>>>(ctxb, Wo, bo, ob_, SEQL, DM, DM, 0);
    }
}

// Round 3
// 440.782 us; speedup vs baseline: 20.6684x; 20.6684x over previous
//
#include <hip/hip_runtime.h>
#include <hip/hip_bf16.h>
#include <math.h>

#define HN 16
#define DM 1024
#define DK 64
#define BSZ 8
#define SEQL 1024

typedef __attribute__((ext_vector_type(8))) short bf16x8;
typedef __attribute__((ext_vector_type(4))) short short4v;
typedef __attribute__((ext_vector_type(4))) float f32x4;

__device__ __forceinline__ short f2bf(float f) {
    union { float f; unsigned u; } x; x.f = f;
    unsigned u = x.u + 0x7FFFu + ((x.u >> 16) & 1u);
    return (short)(u >> 16);
}

// ---------------------------------------------------------------------------
// Wt[n][k] = bf16(W[k][n]), 1024x1024, LDS-tiled transpose (coalesced both sides)
// ---------------------------------------------------------------------------
__global__ __launch_bounds__(256) void transpose_cast(const float* __restrict__ W,
                                                      short* __restrict__ Wt) {
    __shared__ float tile[32][33];
    const int t = threadIdx.x;
    const int k0 = blockIdx.x * 32, n0 = blockIdx.y * 32;
    const int c = t & 31, r = t >> 5;  // 8 rows per pass
    #pragma unroll
    for (int p = 0; p < 4; ++p)
        tile[r + 8 * p][c] = W[(size_t)(k0 + r + 8 * p) * DM + n0 + c];
    __syncthreads();
    #pragma unroll
    for (int p = 0; p < 4; ++p)
        Wt[(size_t)(n0 + r + 8 * p) * DM + k0 + c] = f2bf(tile[c][r + 8 * p]);
}

// ---------------------------------------------------------------------------
// MFMA GEMM, M=N=K=1024 per batch (z = batch). 128x128 tile, BK=32,
// 256 thr = 4 waves (2x2), each wave 64x64 = 4x4 C-frags of 16x16x32 bf16.
// MODE 0: A fp32 row-major; C = bf16, head-split [h][s][dk] (+bias)
// MODE 1: A bf16 row-major; C = fp32 row-major [s][n] (+bias)
// Wt is bf16 [n][k] (pre-transposed).
// ---------------------------------------------------------------------------
template <int MODE>
__global__ __launch_bounds__(256) void gemm_mfma(const void* __restrict__ Ap,
                                                 const short* __restrict__ Wt,
                                                 const float* __restrict__ bias,
                                                 void* __restrict__ Cp) {
    __shared__ __attribute__((aligned(16))) short As[128][40];  // +8 pad: 2-way banks
    __shared__ __attribute__((aligned(16))) short Bs[128][40];
    const int t = threadIdx.x;
    const int lane = t & 63, wv = t >> 6;
    const int wm = (wv >> 1) * 64, wn = (wv & 1) * 64;
    const int quad = lane >> 4, l15 = lane & 15;
    const int tileM = blockIdx.x * 128, tileN = blockIdx.y * 128;
    const size_t zoff = (size_t)blockIdx.z * DM * SEQL;

    f32x4 acc[4][4];
    #pragma unroll
    for (int i = 0; i < 4; ++i)
        #pragma unroll
        for (int j = 0; j < 4; ++j) acc[i][j] = {0.f, 0.f, 0.f, 0.f};

    for (int k0 = 0; k0 < DM; k0 += 32) {
        if (MODE == 0) {
            const float* A = (const float*)Ap + zoff;
            const int r0 = t >> 3, c4 = (t & 7) * 4;
            #pragma unroll
            for (int p = 0; p < 4; ++p) {
                int row = r0 + 32 * p;
                float4 v = *(const float4*)(A + (size_t)(tileM + row) * DM + k0 + c4);
                short4v s4 = {f2bf(v.x), f2bf(v.y), f2bf(v.z), f2bf(v.w)};
                *(short4v*)&As[row][c4] = s4;
            }
        } else {
            const short* A = (const short*)Ap + zoff;
            const int r0 = t >> 2, c8 = (t & 3) * 8;
            #pragma unroll
            for (int p = 0; p < 2; ++p) {
                int row = r0 + 64 * p;
                *(bf16x8*)&As[row][c8] =
                    *(const bf16x8*)(A + (size_t)(tileM + row) * DM + k0 + c8);
            }
        }
        {
            const int r0 = t >> 2, c8 = (t & 3) * 8;
            #pragma unroll
            for (int p = 0; p < 2; ++p) {
                int row = r0 + 64 * p;
                *(bf16x8*)&Bs[row][c8] =
                    *(const bf16x8*)(Wt + (size_t)(tileN + row) * DM + k0 + c8);
            }
        }
        __syncthreads();
        bf16x8 a[4], b[4];
        #pragma unroll
        for (int i = 0; i < 4; ++i) a[i] = *(const bf16x8*)&As[wm + i * 16 + l15][quad * 8];
        #pragma unroll
        for (int j = 0; j < 4; ++j) b[j] = *(const bf16x8*)&Bs[wn + j * 16 + l15][quad * 8];
        #pragma unroll
        for (int i = 0; i < 4; ++i)
            #pragma unroll
            for (int j = 0; j < 4; ++j)
                acc[i][j] = __builtin_amdgcn_mfma_f32_16x16x32_bf16(a[i], b[j], acc[i][j], 0, 0, 0);
        __syncthreads();
    }

    // epilogue: C/D layout col=lane&15, row=quad*4+reg  [m89-verified]
    #pragma unroll
    for (int i = 0; i < 4; ++i)
        #pragma unroll
        for (int j = 0; j < 4; ++j)
            #pragma unroll
            for (int rr = 0; rr < 4; ++rr) {
                int row = tileM + wm + i * 16 + quad * 4 + rr;
                int col = tileN + wn + j * 16 + l15;
                float v = acc[i][j][rr] + bias[col];
                if (MODE == 0) {
                    short* C = (short*)Cp + zoff;
                    C[((size_t)(col >> 6) * SEQL + row) * DK + (col & 63)] = f2bf(v);
                } else {
                    float* C = (float*)Cp + zoff;
                    C[(size_t)row * DM + col] = v;
                }
            }
}

// ---------------------------------------------------------------------------
// MFMA attention. Block = (qtile of 64, h, batch), 256 thr = 4 waves; wave w
// owns q rows q0+16w..+15. Unnormalized accumulation (masked p=0, no max
// subtraction: scores bounded, softmax shift-invariant), divide by L at end.
// ---------------------------------------------------------------------------
__global__ __launch_bounds__(256) void attn_mfma(const short* __restrict__ Qw,
                                                 const short* __restrict__ Kw,
                                                 const short* __restrict__ Vw,
                                                 const int* __restrict__ mask,
                                                 short* __restrict__ ctx) {
    __shared__ __attribute__((aligned(16))) short Qs[64][72];
    __shared__ __attribute__((aligned(16))) short Ks[64][72];
    __shared__ __attribute__((aligned(16))) short Vs[64][72];     // transposed: [d][j]
    __shared__ __attribute__((aligned(16))) short Ps[4][16][72];  // per-wave P
    const int t = threadIdx.x;
    const int lane = t & 63, w = t >> 6;
    const int quad = lane >> 4, l15 = lane & 15;
    const int q0 = blockIdx.x * 64;
    const int h = blockIdx.y;
    const size_t zoff = (size_t)blockIdx.z * DM * SEQL;
    const short* Qb = Qw + zoff + (size_t)h * SEQL * DK;
    const short* Kb = Kw + zoff + (size_t)h * SEQL * DK;
    const short* Vb = Vw + zoff + (size_t)h * SEQL * DK;
    const int* mb = mask + (size_t)blockIdx.z * SEQL * SEQL;

    #pragma unroll
    for (int p = 0; p < 2; ++p) {
        int cc = t + 256 * p;
        int row = cc >> 3, off = (cc & 7) * 8;
        *(bf16x8*)&Qs[row][off] = *(const bf16x8*)(Qb + (size_t)(q0 + row) * DK + off);
    }

    f32x4 o[4];
    #pragma unroll
    for (int td = 0; td < 4; ++td) o[td] = {0.f, 0.f, 0.f, 0.f};
    float Lacc[4] = {0.f, 0.f, 0.f, 0.f};

    for (int j0 = 0; j0 < SEQL; j0 += 64) {
        #pragma unroll
        for (int p = 0; p < 2; ++p) {
            int cc = t + 256 * p;
            int row = cc >> 3, off = (cc & 7) * 8;
            *(bf16x8*)&Ks[row][off] = *(const bf16x8*)(Kb + (size_t)(j0 + row) * DK + off);
        }
        {   // V tile transposed into Vs[d][j]
            int r = t >> 2, c16 = (t & 3) * 16;
            bf16x8 v0 = *(const bf16x8*)(Vb + (size_t)(j0 + r) * DK + c16);
            bf16x8 v1 = *(const bf16x8*)(Vb + (size_t)(j0 + r) * DK + c16 + 8);
            #pragma unroll
            for (int u = 0; u < 8; ++u) Vs[c16 + u][r] = v0[u];
            #pragma unroll
            for (int u = 0; u < 8; ++u) Vs[c16 + 8 + u][r] = v1[u];
        }
        __syncthreads();

        #pragma unroll
        for (int tn = 0; tn < 4; ++tn) {
            f32x4 s = {0.f, 0.f, 0.f, 0.f};
            #pragma unroll
            for (int ks = 0; ks < 2; ++ks) {
                bf16x8 aq = *(const bf16x8*)&Qs[w * 16 + l15][ks * 32 + quad * 8];
                bf16x8 bk = *(const bf16x8*)&Ks[tn * 16 + l15][ks * 32 + quad * 8];
                s = __builtin_amdgcn_mfma_f32_16x16x32_bf16(aq, bk, s, 0, 0, 0);
            }
            #pragma unroll
            for (int rr = 0; rr < 4; ++rr) {
                int rq = q0 + w * 16 + quad * 4 + rr;
                int cj = j0 + tn * 16 + l15;
                float p = mb[(size_t)rq * SEQL + cj] ? __expf(s[rr] * 0.125f) : 0.0f;
                Lacc[rr] += p;
                Ps[w][quad * 4 + rr][tn * 16 + l15] = f2bf(p);
            }
        }
        __syncthreads();  // Ps C-layout -> A-layout round trip

        #pragma unroll
        for (int td = 0; td < 4; ++td)
            #pragma unroll
            for (int ks = 0; ks < 2; ++ks) {
                bf16x8 ap = *(const bf16x8*)&Ps[w][l15][ks * 32 + quad * 8];
                bf16x8 bv = *(const bf16x8*)&Vs[td * 16 + l15][ks * 32 + quad * 8];
                o[td] = __builtin_amdgcn_mfma_f32_16x16x32_bf16(ap, bv, o[td], 0, 0, 0);
            }
        __syncthreads();  // before restaging Ks/Vs
    }

    #pragma unroll
    for (int rr = 0; rr < 4; ++rr) {
        float l = Lacc[rr];
        l += __shfl_xor(l, 1);
        l += __shfl_xor(l, 2);
        l += __shfl_xor(l, 4);
        l += __shfl_xor(l, 8);
        Lacc[rr] = 1.0f / l;
    }
    short* cb = ctx + zoff;
    #pragma unroll
    for (int td = 0; td < 4; ++td)
        #pragma unroll
        for (int rr = 0; rr < 4; ++rr) {
            int rq = q0 + w * 16 + quad * 4 + rr;
            int cd = h * 64 + td * 16 + l15;
            cb[(size_t)rq * DM + cd] = f2bf(o[td][rr] * Lacc[rr]);
        }
}

extern "C" void kernel_launch(void* const* d_in, const int* in_sizes, int n_in,
                              void* d_out, int out_size, void* d_ws, size_t ws_size,
                              hipStream_t stream) {
    const float* q  = (const float*)d_in[0];
    const float* k  = (const float*)d_in[1];
    const float* v  = (const float*)d_in[2];
    const int* mask = (const int*)d_in[3];
    const float* Wq = (const float*)d_in[4];
    const float* bq = (const float*)d_in[5];
    const float* Wk = (const float*)d_in[6];
    const float* bk = (const float*)d_in[7];
    const float* Wv = (const float*)d_in[8];
    const float* bv = (const float*)d_in[9];
    const float* Wo = (const float*)d_in[10];
    const float* bo = (const float*)d_in[11];
    float* out = (float*)d_out;

    const size_t MEL = (size_t)1024 * 1024;  // 1M elements
    short* wsb = (short*)d_ws;
    short* Wqt = wsb;
    short* Wkt = wsb + MEL;
    short* Wvt = wsb + 2 * MEL;
    short* Wot = wsb + 3 * MEL;

    transpose_cast<<<dim3(32, 32), 256, 0, stream>>>(Wq, Wqt);
    transpose_cast<<<dim3(32, 32), 256, 0, stream>>>(Wk, Wkt);
    transpose_cast<<<dim3(32, 32), 256, 0, stream>>>(Wv, Wvt);
    transpose_cast<<<dim3(32, 32), 256, 0, stream>>>(Wo, Wot);

    const bool full = ws_size >= ((size_t)80 << 20);  // full layout needs 72 MB
    const int zdim = full ? BSZ : 1;
    const int iters = full ? 1 : BSZ;

    // full: Qw/Kw/Vw/ctx hold all 8 batches (8M el each); per-batch: 1M el each
    const size_t bufEl = full ? 8 * MEL : MEL;
    short* Qw  = wsb + 4 * MEL;
    short* Kw  = Qw + bufEl;
    short* Vw  = Kw + bufEl;
    short* ctx = Vw + bufEl;

    for (int it = 0; it < iters; ++it) {
        const float* qb = q + (size_t)it * MEL;
        const float* kb = k + (size_t)it * MEL;
        const float* vb = v + (size_t)it * MEL;
        const int* mbp  = mask + (size_t)it * MEL;
        float* ob       = out + (size_t)it * MEL;

        gemm_mfma<0><<<dim3(8, 8, zdim), 256, 0, stream>>>(qb, Wqt, bq, Qw);
        gemm_mfma<0><<<dim3(8, 8, zdim), 256, 0, stream>>>(kb, Wkt, bk, Kw);
        gemm_mfma<0><<<dim3(8, 8, zdim), 256, 0, stream>>>(vb, Wvt, bv, Vw);

        attn_mfma<<<dim3(16, 16, zdim), 256, 0, stream>>>(Qw, Kw, Vw, mbp, ctx);

        gemm_mfma<1><<<dim3(8, 8, zdim), 256, 0, stream>>>(ctx, Wot, bo, ob);
    }
}

// Round 4
// 437.362 us; speedup vs baseline: 20.8300x; 1.0078x over previous
//
#include <hip/hip_runtime.h>
#include <hip/hip_bf16.h>

#define HN 16
#define DM 1024
#define DK 64
#define BSZ 8
#define SEQL 1024

typedef __attribute__((ext_vector_type(8))) short bf16x8;
typedef __attribute__((ext_vector_type(4))) short short4v;
typedef __attribute__((ext_vector_type(4))) float f32x4;

__device__ __forceinline__ short f2bf(float f) {
    union { float f; unsigned u; } x; x.f = f;
    unsigned u = x.u + 0x7FFFu + ((x.u >> 16) & 1u);
    return (short)(u >> 16);
}

// ---------------------------------------------------------------------------
// Wt[n][k] = bf16(W[k][n])
// ---------------------------------------------------------------------------
__global__ __launch_bounds__(256) void transpose_cast(const float* __restrict__ W,
                                                      short* __restrict__ Wt) {
    __shared__ float tile[32][33];
    const int t = threadIdx.x;
    const int k0 = blockIdx.x * 32, n0 = blockIdx.y * 32;
    const int c = t & 31, r = t >> 5;
    #pragma unroll
    for (int p = 0; p < 4; ++p)
        tile[r + 8 * p][c] = W[(size_t)(k0 + r + 8 * p) * DM + n0 + c];
    __syncthreads();
    #pragma unroll
    for (int p = 0; p < 4; ++p)
        Wt[(size_t)(n0 + r + 8 * p) * DM + k0 + c] = f2bf(tile[c][r + 8 * p]);
}

// ---------------------------------------------------------------------------
// mask int32[8M] -> bits u64[128K] (1 = keep)
// ---------------------------------------------------------------------------
__global__ __launch_bounds__(256) void pack_mask(const int* __restrict__ mask,
                                                 unsigned long long* __restrict__ bits) {
    size_t i = (size_t)blockIdx.x * 256 + threadIdx.x;
    unsigned long long b = __ballot(mask[i] != 0);
    if ((threadIdx.x & 63) == 0) bits[i >> 6] = b;
}

// ---------------------------------------------------------------------------
// MFMA GEMM, 1024x1024x1024 per z. 128x128 tile, BK=32, 4 waves, 4x4 frags.
// MODE 0: A fp32 -> C bf16 head-split [h][s][dk]   (QKV projections, Q/K)
// MODE 1: A bf16 -> C fp32 row-major  [s][n]       (output projection)
// MODE 2: A fp32 -> C bf16 V-transposed [h][dk][s] (V projection)
// Wt is bf16 [n][k].
// ---------------------------------------------------------------------------
template <int MODE>
__global__ __launch_bounds__(256) void gemm_mfma(const void* __restrict__ Ap,
                                                 const short* __restrict__ Wt,
                                                 const float* __restrict__ bias,
                                                 void* __restrict__ Cp) {
    __shared__ __attribute__((aligned(16))) short As[128][40];
    __shared__ __attribute__((aligned(16))) short Bs[128][40];
    const int t = threadIdx.x;
    const int lane = t & 63, wv = t >> 6;
    const int wm = (wv >> 1) * 64, wn = (wv & 1) * 64;
    const int quad = lane >> 4, l15 = lane & 15;
    const int tileM = blockIdx.x * 128, tileN = blockIdx.y * 128;
    const size_t zoff = (size_t)blockIdx.z * DM * SEQL;

    f32x4 acc[4][4];
    #pragma unroll
    for (int i = 0; i < 4; ++i)
        #pragma unroll
        for (int j = 0; j < 4; ++j) acc[i][j] = {0.f, 0.f, 0.f, 0.f};

    for (int k0 = 0; k0 < DM; k0 += 32) {
        if (MODE != 1) {
            const float* A = (const float*)Ap + zoff;
            const int r0 = t >> 3, c4 = (t & 7) * 4;
            #pragma unroll
            for (int p = 0; p < 4; ++p) {
                int row = r0 + 32 * p;
                float4 v = *(const float4*)(A + (size_t)(tileM + row) * DM + k0 + c4);
                short4v s4 = {f2bf(v.x), f2bf(v.y), f2bf(v.z), f2bf(v.w)};
                *(short4v*)&As[row][c4] = s4;
            }
        } else {
            const short* A = (const short*)Ap + zoff;
            const int r0 = t >> 2, c8 = (t & 3) * 8;
            #pragma unroll
            for (int p = 0; p < 2; ++p) {
                int row = r0 + 64 * p;
                *(bf16x8*)&As[row][c8] =
                    *(const bf16x8*)(A + (size_t)(tileM + row) * DM + k0 + c8);
            }
        }
        {
            const int r0 = t >> 2, c8 = (t & 3) * 8;
            #pragma unroll
            for (int p = 0; p < 2; ++p) {
                int row = r0 + 64 * p;
                *(bf16x8*)&Bs[row][c8] =
                    *(const bf16x8*)(Wt + (size_t)(tileN + row) * DM + k0 + c8);
            }
        }
        __syncthreads();
        bf16x8 a[4], b[4];
        #pragma unroll
        for (int i = 0; i < 4; ++i) a[i] = *(const bf16x8*)&As[wm + i * 16 + l15][quad * 8];
        #pragma unroll
        for (int j = 0; j < 4; ++j) b[j] = *(const bf16x8*)&Bs[wn + j * 16 + l15][quad * 8];
        #pragma unroll
        for (int i = 0; i < 4; ++i)
            #pragma unroll
            for (int j = 0; j < 4; ++j)
                acc[i][j] = __builtin_amdgcn_mfma_f32_16x16x32_bf16(a[i], b[j], acc[i][j], 0, 0, 0);
        __syncthreads();
    }

    #pragma unroll
    for (int i = 0; i < 4; ++i)
        #pragma unroll
        for (int j = 0; j < 4; ++j)
            #pragma unroll
            for (int rr = 0; rr < 4; ++rr) {
                int row = tileM + wm + i * 16 + quad * 4 + rr;
                int col = tileN + wn + j * 16 + l15;
                float v = acc[i][j][rr] + bias[col];
                if (MODE == 0) {
                    short* C = (short*)Cp + zoff;
                    C[((size_t)(col >> 6) * SEQL + row) * DK + (col & 63)] = f2bf(v);
                } else if (MODE == 1) {
                    float* C = (float*)Cp + zoff;
                    C[(size_t)row * DM + col] = v;
                } else {
                    short* C = (short*)Cp + zoff;
                    C[(size_t)col * SEQL + row] = f2bf(v);  // [h][dk][s]
                }
            }
}

// ---------------------------------------------------------------------------
// MFMA attention. Block = (qtile 64, h, z). Q/K head-split [h][s][dk];
// V pre-transposed [h][dk][s]. Unnormalized softmax (masked p=0), /L at end.
// ---------------------------------------------------------------------------
template <bool USE_BITS>
__global__ __launch_bounds__(256) void attn_mfma(const short* __restrict__ Qw,
                                                 const short* __restrict__ Kw,
                                                 const short* __restrict__ Vt,
                                                 const void* __restrict__ maskp,
                                                 short* __restrict__ ctx) {
    __shared__ __attribute__((aligned(16))) short Qs[64][72];
    __shared__ __attribute__((aligned(16))) short Ks[64][72];
    __shared__ __attribute__((aligned(16))) short Vs[64][72];     // [d][j]
    __shared__ __attribute__((aligned(16))) short Ps[4][16][72];  // per-wave
    const int t = threadIdx.x;
    const int lane = t & 63, w = t >> 6;
    const int quad = lane >> 4, l15 = lane & 15;
    const int q0 = blockIdx.x * 64;
    const int h = blockIdx.y;
    const size_t zoff = (size_t)blockIdx.z * DM * SEQL;
    const short* Qb = Qw + zoff + (size_t)h * SEQL * DK;
    const short* Kb = Kw + zoff + (size_t)h * SEQL * DK;
    const short* Vb = Vt + zoff + (size_t)h * DK * SEQL;

    #pragma unroll
    for (int p = 0; p < 2; ++p) {
        int cc = t + 256 * p;
        int row = cc >> 3, off = (cc & 7) * 8;
        *(bf16x8*)&Qs[row][off] = *(const bf16x8*)(Qb + (size_t)(q0 + row) * DK + off);
    }

    f32x4 o[4];
    #pragma unroll
    for (int td = 0; td < 4; ++td) o[td] = {0.f, 0.f, 0.f, 0.f};
    float Lacc[4] = {0.f, 0.f, 0.f, 0.f};

    for (int j0 = 0; j0 < SEQL; j0 += 64) {
        #pragma unroll
        for (int p = 0; p < 2; ++p) {
            int cc = t + 256 * p;
            int row = cc >> 3, off = (cc & 7) * 8;
            *(bf16x8*)&Ks[row][off] = *(const bf16x8*)(Kb + (size_t)(j0 + row) * DK + off);
            *(bf16x8*)&Vs[row][off] = *(const bf16x8*)(Vb + (size_t)row * SEQL + j0 + off);
        }
        __syncthreads();

        unsigned long long mw[4];
        if (USE_BITS) {
            const unsigned long long* mb =
                (const unsigned long long*)maskp + (size_t)blockIdx.z * SEQL * 16;
            #pragma unroll
            for (int rr = 0; rr < 4; ++rr)
                mw[rr] = mb[(size_t)(q0 + w * 16 + quad * 4 + rr) * 16 + (j0 >> 6)];
        }

        #pragma unroll
        for (int tn = 0; tn < 4; ++tn) {
            f32x4 s = {0.f, 0.f, 0.f, 0.f};
            #pragma unroll
            for (int ks = 0; ks < 2; ++ks) {
                bf16x8 aq = *(const bf16x8*)&Qs[w * 16 + l15][ks * 32 + quad * 8];
                bf16x8 bk = *(const bf16x8*)&Ks[tn * 16 + l15][ks * 32 + quad * 8];
                s = __builtin_amdgcn_mfma_f32_16x16x32_bf16(aq, bk, s, 0, 0, 0);
            }
            #pragma unroll
            for (int rr = 0; rr < 4; ++rr) {
                bool keep;
                if (USE_BITS) {
                    keep = (mw[rr] >> (tn * 16 + l15)) & 1ull;
                } else {
                    const int* mb = (const int*)maskp + (size_t)blockIdx.z * SEQL * SEQL;
                    keep = mb[(size_t)(q0 + w * 16 + quad * 4 + rr) * SEQL + j0 + tn * 16 + l15] != 0;
                }
                float p = keep ? __expf(s[rr] * 0.125f) : 0.0f;
                Lacc[rr] += p;
                Ps[w][quad * 4 + rr][tn * 16 + l15] = f2bf(p);
            }
        }
        // Ps is wave-private: no barrier needed before reading it back.
        #pragma unroll
        for (int td = 0; td < 4; ++td)
            #pragma unroll
            for (int ks = 0; ks < 2; ++ks) {
                bf16x8 ap = *(const bf16x8*)&Ps[w][l15][ks * 32 + quad * 8];
                bf16x8 bv = *(const bf16x8*)&Vs[td * 16 + l15][ks * 32 + quad * 8];
                o[td] = __builtin_amdgcn_mfma_f32_16x16x32_bf16(ap, bv, o[td], 0, 0, 0);
            }
        __syncthreads();  // all reads of Ks/Vs done before restage
    }

    #pragma unroll
    for (int rr = 0; rr < 4; ++rr) {
        float l = Lacc[rr];
        l += __shfl_xor(l, 1);
        l += __shfl_xor(l, 2);
        l += __shfl_xor(l, 4);
        l += __shfl_xor(l, 8);
        Lacc[rr] = 1.0f / l;
    }
    short* cb = ctx + zoff;
    #pragma unroll
    for (int td = 0; td < 4; ++td)
        #pragma unroll
        for (int rr = 0; rr < 4; ++rr) {
            int rq = q0 + w * 16 + quad * 4 + rr;
            int cd = h * 64 + td * 16 + l15;
            cb[(size_t)rq * DM + cd] = f2bf(o[td][rr] * Lacc[rr]);
        }
}

extern "C" void kernel_launch(void* const* d_in, const int* in_sizes, int n_in,
                              void* d_out, int out_size, void* d_ws, size_t ws_size,
                              hipStream_t stream) {
    const float* q  = (const float*)d_in[0];
    const float* k  = (const float*)d_in[1];
    const float* v  = (const float*)d_in[2];
    const int* mask = (const int*)d_in[3];
    const float* Wq = (const float*)d_in[4];
    const float* bq = (const float*)d_in[5];
    const float* Wk = (const float*)d_in[6];
    const float* bk = (const float*)d_in[7];
    const float* Wv = (const float*)d_in[8];
    const float* bv = (const float*)d_in[9];
    const float* Wo = (const float*)d_in[10];
    const float* bo = (const float*)d_in[11];
    float* out = (float*)d_out;

    const size_t MB = (size_t)1 << 20;
    const size_t MEL = (size_t)1024 * 1024;
    char* base = (char*)d_ws;

    short* Wqt = (short*)(base + 0 * 2 * MB);
    short* Wkt = (short*)(base + 1 * 2 * MB);
    short* Wvt = (short*)(base + 2 * 2 * MB);
    short* Wot = (short*)(base + 3 * 2 * MB);

    // tiers: weights 8MB [+ bits 1MB] + 4 bufs * z * 2MB
    int zdim;
    bool use_bits;
    if      (ws_size >= 74 * MB) { zdim = 8; use_bits = true; }
    else if (ws_size >= 42 * MB) { zdim = 4; use_bits = true; }
    else if (ws_size >= 26 * MB) { zdim = 2; use_bits = true; }
    else if (ws_size >= 18 * MB) { zdim = 1; use_bits = true; }
    else                         { zdim = 1; use_bits = false; }

    unsigned long long* bits = (unsigned long long*)(base + 8 * MB);
    char* bufs = base + (use_bits ? 9 : 8) * MB;
    const size_t bufB = (size_t)zdim * 2 * MB;
    short* Qw  = (short*)(bufs);
    short* Kw  = (short*)(bufs + bufB);
    short* Vw  = (short*)(bufs + 2 * bufB);
    short* ctx = (short*)(bufs + 3 * bufB);

    transpose_cast<<<dim3(32, 32), 256, 0, stream>>>(Wq, Wqt);
    transpose_cast<<<dim3(32, 32), 256, 0, stream>>>(Wk, Wkt);
    transpose_cast<<<dim3(32, 32), 256, 0, stream>>>(Wv, Wvt);
    transpose_cast<<<dim3(32, 32), 256, 0, stream>>>(Wo, Wot);
    if (use_bits)
        pack_mask<<<(BSZ * SEQL * SEQL) / 256, 256, 0, stream>>>(mask, bits);

    const int iters = BSZ / zdim;
    for (int it = 0; it < iters; ++it) {
        const size_t boff = (size_t)it * zdim * MEL;
        const float* qb = q + boff;
        const float* kb = k + boff;
        const float* vb = v + boff;
        float* ob = out + boff;
        const void* mb = use_bits
            ? (const void*)(bits + (size_t)it * zdim * SEQL * 16)
            : (const void*)(mask + (size_t)it * zdim * SEQL * SEQL);

        gemm_mfma<0><<<dim3(8, 8, zdim), 256, 0, stream>>>(qb, Wqt, bq, Qw);
        gemm_mfma<0><<<dim3(8, 8, zdim), 256, 0, stream>>>(kb, Wkt, bk, Kw);
        gemm_mfma<2><<<dim3(8, 8, zdim), 256, 0, stream>>>(vb, Wvt, bv, Vw);

        if (use_bits)
            attn_mfma<true><<<dim3(16, 16, zdim), 256, 0, stream>>>(Qw, Kw, Vw, mb, ctx);
        else
            attn_mfma<false><<<dim3(16, 16, zdim), 256, 0, stream>>>(Qw, Kw, Vw, mb, ctx);

        gemm_mfma<1><<<dim3(8, 8, zdim), 256, 0, stream>>>(ctx, Wot, bo, ob);
    }
}